// Round 3
// baseline (1021.560 us; speedup 1.0000x reference)
//
#include <hip/hip_runtime.h>
#include <hip/hip_bf16.h>

#define DI static __device__ __forceinline__

// may_alias: these vectors reinterpret ushort/float storage.
typedef __attribute__((ext_vector_type(8), may_alias)) short short8;
typedef __attribute__((ext_vector_type(4), may_alias)) float floatx4a;
typedef __attribute__((ext_vector_type(4))) float floatx4;

constexpr int Bsz = 64, Nseq = 512, Cdim = 768, NH = 12, HD = 64;
constexpr int QS = Bsz * NH * Nseq * HD;  // 25165824 elems per q/k/v buffer
constexpr float SCALE = 0.125f;           // hd^-0.5

DI ushort f2bf(float f) {
  union { float f; unsigned u; } v; v.f = f;
  unsigned r = v.u + 0x7FFF + ((v.u >> 16) & 1);   // RNE
  return (ushort)(r >> 16);
}
DI float bf2f(ushort u) {
  union { unsigned u; float f; } v; v.u = ((unsigned)u) << 16;
  return v.f;
}

// Adaptive 8-element row load -> bf16 lane vector. ei must be a multiple of 8.
DI short8 load8(const void* p, size_t ei, int f32) {
  if (f32) {
    const float* f = (const float*)p + ei;
    floatx4a a = *(const floatx4a*)f;
    floatx4a b = *(const floatx4a*)(f + 4);
    short8 r;
    r[0] = (short)f2bf(a[0]); r[1] = (short)f2bf(a[1]);
    r[2] = (short)f2bf(a[2]); r[3] = (short)f2bf(a[3]);
    r[4] = (short)f2bf(b[0]); r[5] = (short)f2bf(b[1]);
    r[6] = (short)f2bf(b[2]); r[7] = (short)f2bf(b[3]);
    return r;
  }
  return *(const short8*)((const ushort*)p + ei);
}
DI float loadf(const void* p, size_t i, int f32) {
  return f32 ? ((const float*)p)[i] : bf2f(((const ushort*)p)[i]);
}

// ---------------- Stage 0: runtime input-dtype detection --------------------
// bf16 N(0,1) data: exponent field clustered ~[90,140]. fp32 read as ushorts:
// even indices are low mantissa halves = uniform bits -> ~80% outside band.
__global__ void detect_dtype(const ushort* __restrict__ x, int* __restrict__ flag) {
  __shared__ int acc;
  int t = threadIdx.x;
  if (t == 0) acc = 0;
  __syncthreads();
  int wild = 0;
  for (int i = t; i < 2048; i += 256) {
    ushort u = x[2 * i];          // first 4096 ushorts: safe for both dtypes
    int e = (u >> 7) & 0xFF;
    int plaus = (u == 0) || (e >= 90 && e <= 140);
    wild += !plaus;
  }
  atomicAdd(&acc, wild);
  __syncthreads();
  if (t == 0) *flag = (acc > 400) ? 1 : 0;   // 1 = inputs are fp32
}

// ---------------- Stage 1: qkv = x @ qkv_w^T, scatter to q/k/v [B,H,N,hd] ----
__global__ __launch_bounds__(256) void qkv_gemm(
    const void* __restrict__ x, const void* __restrict__ w,
    const int* __restrict__ flagp,
    ushort* __restrict__ qo, ushort* __restrict__ ko, ushort* __restrict__ vo)
{
  __shared__ __align__(16) ushort As[64 * 72];   // +8 bf16 pad: row stride 144B
  __shared__ __align__(16) ushort Ws[64 * 72];
  const int f32 = *flagp;
  const int bn = blockIdx.x;       // 0..35  (2304/64)
  const int bm = blockIdx.y;       // 0..511 (32768/64)
  const int t = threadIdx.x;
  const int wv = t >> 6, ln = t & 63, lq = ln >> 4, lm = ln & 15;

  floatx4 acc[4];
  #pragma unroll
  for (int i = 0; i < 4; ++i) acc[i] = (floatx4)0.f;

  for (int kt = 0; kt < Cdim / 64; ++kt) {
    #pragma unroll
    for (int i = 0; i < 2; ++i) {
      int id = t + 256 * i;
      int r = id >> 3, c = (id & 7) << 3;
      *(short8*)&As[r * 72 + c] =
          load8(x, (size_t)(bm * 64 + r) * Cdim + kt * 64 + c, f32);
      *(short8*)&Ws[r * 72 + c] =
          load8(w, (size_t)(bn * 64 + r) * Cdim + kt * 64 + c, f32);
    }
    __syncthreads();
    #pragma unroll
    for (int ks = 0; ks < 2; ++ks) {
      short8 a = *(const short8*)&As[(wv * 16 + lm) * 72 + ks * 32 + lq * 8];
      #pragma unroll
      for (int cb = 0; cb < 4; ++cb) {
        short8 bfr = *(const short8*)&Ws[(cb * 16 + lm) * 72 + ks * 32 + lq * 8];
        acc[cb] = __builtin_amdgcn_mfma_f32_16x16x32_bf16(a, bfr, acc[cb], 0, 0, 0);
      }
    }
    __syncthreads();
  }

  // col n = bn*64 + cb*16 + lm -> which = bn/12, h = bn%12, d = cb*16+lm
  const int which = bn / NH, h = bn % NH;
  ushort* outp = which == 0 ? qo : (which == 1 ? ko : vo);
  #pragma unroll
  for (int cb = 0; cb < 4; ++cb) {
    int d = cb * 16 + lm;
    #pragma unroll
    for (int r = 0; r < 4; ++r) {
      int gm = bm * 64 + wv * 16 + lq * 4 + r;
      int b = gm >> 9, ns = gm & 511;
      outp[(size_t)((b * NH + h) * Nseq + ns) * HD + d] = f2bf(acc[cb][r]);
    }
  }
}

// ---------------- Stage 2: flash attention per (b,h,q-tile of 64) -----------
__global__ __launch_bounds__(256) void attn_kernel(
    const ushort* __restrict__ q, const ushort* __restrict__ k,
    const ushort* __restrict__ v, const void* __restrict__ bt,
    const int* __restrict__ flagp, ushort* __restrict__ ao)
{
  __shared__ __align__(16) ushort Qs[64 * 72];
  __shared__ __align__(16) ushort Ks[64 * 72];
  __shared__ __align__(16) ushort Vs[64 * 72];
  __shared__ __align__(16) ushort Ps[64 * 72];
  const int f32 = *flagp;
  const int blk = blockIdx.x;
  const int qt = blk & 7;          // q-tile 0..7
  const int bh = blk >> 3;         // b*12 + h
  const int h = bh % NH, b = bh / NH;
  const int t = threadIdx.x;
  const int wv = t >> 6, ln = t & 63, lq = ln >> 4, lm = ln & 15;
  const size_t base = (size_t)bh * (Nseq * HD);

  #pragma unroll
  for (int i = 0; i < 2; ++i) {
    int id = t + 256 * i;
    int r = id >> 3, c = (id & 7) << 3;
    *(short8*)&Qs[r * 72 + c] =
        *(const short8*)&q[base + (size_t)(qt * 64 + r) * HD + c];
  }

  floatx4 o[4];
  #pragma unroll
  for (int i = 0; i < 4; ++i) o[i] = (floatx4)0.f;
  float mrow[4], lrow[4];
  #pragma unroll
  for (int r = 0; r < 4; ++r) { mrow[r] = -1e30f; lrow[r] = 0.f; }

  for (int kt = 0; kt < Nseq / 64; ++kt) {
    #pragma unroll
    for (int i = 0; i < 2; ++i) {
      int id = t + 256 * i;
      int r = id >> 3, c = (id & 7) << 3;
      *(short8*)&Ks[r * 72 + c] =
          *(const short8*)&k[base + (size_t)(kt * 64 + r) * HD + c];
      *(short8*)&Vs[r * 72 + c] =
          *(const short8*)&v[base + (size_t)(kt * 64 + r) * HD + c];
    }
    __syncthreads();

    // S = Q K^T for this wave's 16 q-rows x 64 keys
    floatx4 s[4];
    #pragma unroll
    for (int cb = 0; cb < 4; ++cb) s[cb] = (floatx4)0.f;
    #pragma unroll
    for (int ks = 0; ks < 2; ++ks) {
      short8 a = *(const short8*)&Qs[(wv * 16 + lm) * 72 + ks * 32 + lq * 8];
      #pragma unroll
      for (int cb = 0; cb < 4; ++cb) {
        short8 bfr = *(const short8*)&Ks[(cb * 16 + lm) * 72 + ks * 32 + lq * 8];
        s[cb] = __builtin_amdgcn_mfma_f32_16x16x32_bf16(a, bfr, s[cb], 0, 0, 0);
      }
    }

    // scale + rel-pos bias + online softmax (rows = wv*16 + lq*4 + r)
    float pvals[4][4];
    #pragma unroll
    for (int r = 0; r < 4; ++r) {
      int ig = qt * 64 + wv * 16 + lq * 4 + r;
      float sv[4];
      float vmax = -1e30f;
      #pragma unroll
      for (int cb = 0; cb < 4; ++cb) {
        int jg = kt * 64 + cb * 16 + lm;
        float bias = loadf(bt, (size_t)(ig - jg + Nseq - 1) * NH + h, f32);
        sv[cb] = s[cb][r] * SCALE + bias;
        vmax = fmaxf(vmax, sv[cb]);
      }
      #pragma unroll
      for (int off = 8; off; off >>= 1) vmax = fmaxf(vmax, __shfl_xor(vmax, off));
      float mnew = fmaxf(mrow[r], vmax);
      float alpha = __expf(mrow[r] - mnew);
      float rsum = 0.f;
      #pragma unroll
      for (int cb = 0; cb < 4; ++cb) {
        float p = __expf(sv[cb] - mnew);
        pvals[cb][r] = p;
        rsum += p;
      }
      #pragma unroll
      for (int off = 8; off; off >>= 1) rsum += __shfl_xor(rsum, off);
      lrow[r] = lrow[r] * alpha + rsum;
      mrow[r] = mnew;
      #pragma unroll
      for (int db = 0; db < 4; ++db) o[db][r] *= alpha;
    }

    // P: C-layout -> LDS -> A-layout (each wave owns its 16-row strip)
    #pragma unroll
    for (int cb = 0; cb < 4; ++cb)
      #pragma unroll
      for (int r = 0; r < 4; ++r)
        Ps[(wv * 16 + lq * 4 + r) * 72 + cb * 16 + lm] = f2bf(pvals[cb][r]);

    __syncthreads();   // order Ps scalar stores before vector loads

    // O += P V
    #pragma unroll
    for (int ks = 0; ks < 2; ++ks) {
      short8 a = *(const short8*)&Ps[(wv * 16 + lm) * 72 + ks * 32 + lq * 8];
      #pragma unroll
      for (int db = 0; db < 4; ++db) {
        short8 bfr;
        #pragma unroll
        for (int j = 0; j < 8; ++j)
          bfr[j] = (short)Vs[(ks * 32 + lq * 8 + j) * 72 + db * 16 + lm];
        o[db] = __builtin_amdgcn_mfma_f32_16x16x32_bf16(a, bfr, o[db], 0, 0, 0);
      }
    }
    __syncthreads();
  }

  // epilogue: O / l -> attn_out [B,N,C] with C = h*64 + d
  #pragma unroll
  for (int r = 0; r < 4; ++r) {
    int qi = qt * 64 + wv * 16 + lq * 4 + r;
    float inv = 1.f / lrow[r];
    #pragma unroll
    for (int db = 0; db < 4; ++db) {
      int d = db * 16 + lm;
      ao[(size_t)(b * Nseq + qi) * Cdim + h * HD + d] = f2bf(o[db][r] * inv);
    }
  }
}

// ---------------- Stage 3: out = attn_out @ proj_w^T + proj_b ---------------
__global__ __launch_bounds__(256) void proj_gemm(
    const ushort* __restrict__ a, const void* __restrict__ w,
    const void* __restrict__ pb, const int* __restrict__ flagp,
    void* __restrict__ out)
{
  __shared__ __align__(16) ushort As[64 * 72];
  __shared__ __align__(16) ushort Ws[64 * 72];
  const int f32 = *flagp;
  const int bn = blockIdx.x;   // 0..11
  const int bm = blockIdx.y;   // 0..511
  const int t = threadIdx.x;
  const int wv = t >> 6, ln = t & 63, lq = ln >> 4, lm = ln & 15;

  floatx4 acc[4];
  #pragma unroll
  for (int i = 0; i < 4; ++i) acc[i] = (floatx4)0.f;

  for (int kt = 0; kt < Cdim / 64; ++kt) {
    #pragma unroll
    for (int i = 0; i < 2; ++i) {
      int id = t + 256 * i;
      int r = id >> 3, c = (id & 7) << 3;
      *(short8*)&As[r * 72 + c] =
          *(const short8*)&a[(size_t)(bm * 64 + r) * Cdim + kt * 64 + c];
      *(short8*)&Ws[r * 72 + c] =
          load8(w, (size_t)(bn * 64 + r) * Cdim + kt * 64 + c, f32);
    }
    __syncthreads();
    #pragma unroll
    for (int ks = 0; ks < 2; ++ks) {
      short8 af = *(const short8*)&As[(wv * 16 + lm) * 72 + ks * 32 + lq * 8];
      #pragma unroll
      for (int cb = 0; cb < 4; ++cb) {
        short8 bfr = *(const short8*)&Ws[(cb * 16 + lm) * 72 + ks * 32 + lq * 8];
        acc[cb] = __builtin_amdgcn_mfma_f32_16x16x32_bf16(af, bfr, acc[cb], 0, 0, 0);
      }
    }
    __syncthreads();
  }

  #pragma unroll
  for (int cb = 0; cb < 4; ++cb) {
    int gn = bn * 64 + cb * 16 + lm;
    float bias = loadf(pb, gn, f32);
    #pragma unroll
    for (int r = 0; r < 4; ++r) {
      int gm = bm * 64 + wv * 16 + lq * 4 + r;
      float val = acc[cb][r] + bias;
      size_t idx = (size_t)gm * Cdim + gn;
      if (f32) ((float*)out)[idx] = val;
      else     ((ushort*)out)[idx] = f2bf(val);
    }
  }
}

extern "C" void kernel_launch(void* const* d_in, const int* in_sizes, int n_in,
                              void* d_out, int out_size, void* d_ws, size_t ws_size,
                              hipStream_t stream) {
  const void* x  = d_in[0];   // [64,512,768]  bf16 or fp32 (runtime-detected)
  const void* qw = d_in[1];   // [2304,768]
  const void* pw = d_in[2];   // [768,768]
  const void* pb = d_in[3];   // [768]
  const void* bt = d_in[4];   // [1023,12]

  int* flag = (int*)d_ws;
  ushort* qs = (ushort*)((char*)d_ws + 256);   // canonical bf16 intermediates
  ushort* ks = qs + QS;
  ushort* vs = ks + QS;
  ushort* ao = vs + QS;

  detect_dtype<<<1, 256, 0, stream>>>((const ushort*)x, flag);
  qkv_gemm<<<dim3(36, 512), 256, 0, stream>>>(x, qw, flag, qs, ks, vs);
  attn_kernel<<<dim3(Bsz * NH * (Nseq / 64)), 256, 0, stream>>>(qs, ks, vs, bt, flag, ao);
  proj_gemm<<<dim3(12, 512), 256, 0, stream>>>(ao, pw, pb, flag, d_out);
}

// Round 4
// 599.354 us; speedup vs baseline: 1.7044x; 1.7044x over previous
//
#include <hip/hip_runtime.h>
#include <hip/hip_bf16.h>

#define DI static __device__ __forceinline__

typedef __attribute__((ext_vector_type(8), may_alias)) short short8;
typedef __attribute__((ext_vector_type(4), may_alias)) short short4a;
typedef __attribute__((ext_vector_type(4), may_alias)) float floatx4a;
typedef __attribute__((ext_vector_type(4))) float floatx4;

constexpr int Bsz = 64, Nseq = 512, Cdim = 768, NH = 12, HD = 64;
constexpr int QS = Bsz * NH * Nseq * HD;  // 25165824
constexpr float SCALE = 0.125f;

DI ushort f2bf(float f) {
  union { float f; unsigned u; } v; v.f = f;
  unsigned r = v.u + 0x7FFF + ((v.u >> 16) & 1);
  return (ushort)(r >> 16);
}
DI float bf2f(ushort u) {
  union { unsigned u; float f; } v; v.u = ((unsigned)u) << 16;
  return v.f;
}

// ------------- fp32 -> bf16 converters (inputs are fp32: verified R3) -------
__global__ void cvt8(const float* __restrict__ s, ushort* __restrict__ d, int n) {
  int i = (blockIdx.x * 256 + threadIdx.x) * 8;
  if (i >= n) return;
  floatx4a a = *(const floatx4a*)(s + i);
  floatx4a b = *(const floatx4a*)(s + i + 4);
  short8 r;
  r[0] = (short)f2bf(a[0]); r[1] = (short)f2bf(a[1]);
  r[2] = (short)f2bf(a[2]); r[3] = (short)f2bf(a[3]);
  r[4] = (short)f2bf(b[0]); r[5] = (short)f2bf(b[1]);
  r[6] = (short)f2bf(b[2]); r[7] = (short)f2bf(b[3]);
  *(short8*)(d + i) = r;
}
__global__ void cvt1(const float* __restrict__ s, ushort* __restrict__ d, int n) {
  int i = blockIdx.x * 256 + threadIdx.x;
  if (i < n) d[i] = f2bf(s[i]);
}

// ------------- Stage 1: qkv = x @ qkv_w^T (128x128 tile, m93-class) ---------
// q,k stored [B,H,N,hd]; V stored TRANSPOSED [B,H,hd,N] for vector PV frags.
__global__ __launch_bounds__(256) void qkv_gemm(
    const ushort* __restrict__ x, const ushort* __restrict__ w,
    ushort* __restrict__ qo, ushort* __restrict__ ko, ushort* __restrict__ vo)
{
  __shared__ __align__(16) ushort As[128 * 72];
  __shared__ __align__(16) ushort Ws[128 * 72];
  const int bn = blockIdx.x;   // 0..17  (2304/128)
  const int bm = blockIdx.y;   // 0..255 (32768/128)
  const int t = threadIdx.x;
  const int wv = t >> 6, ln = t & 63, lq = ln >> 4, lm = ln & 15;
  const int wm = wv >> 1, wn = wv & 1;   // wave tile: rows wm*64+, cols wn*64+

  floatx4 acc[4][4];
  #pragma unroll
  for (int i = 0; i < 4; ++i)
    #pragma unroll
    for (int j = 0; j < 4; ++j) acc[i][j] = (floatx4)0.f;

  for (int kt = 0; kt < Cdim / 64; ++kt) {
    #pragma unroll
    for (int i = 0; i < 4; ++i) {
      int id = t + 256 * i;
      int r = id >> 3, c = (id & 7) << 3;
      *(short8*)&As[r * 72 + c] =
          *(const short8*)&x[(size_t)(bm * 128 + r) * Cdim + kt * 64 + c];
      *(short8*)&Ws[r * 72 + c] =
          *(const short8*)&w[(size_t)(bn * 128 + r) * Cdim + kt * 64 + c];
    }
    __syncthreads();
    #pragma unroll
    for (int ks = 0; ks < 2; ++ks) {
      short8 af[4], bfr[4];
      #pragma unroll
      for (int i = 0; i < 4; ++i)
        af[i] = *(const short8*)&As[(wm * 64 + i * 16 + lm) * 72 + ks * 32 + lq * 8];
      #pragma unroll
      for (int j = 0; j < 4; ++j)
        bfr[j] = *(const short8*)&Ws[(wn * 64 + j * 16 + lm) * 72 + ks * 32 + lq * 8];
      #pragma unroll
      for (int i = 0; i < 4; ++i)
        #pragma unroll
        for (int j = 0; j < 4; ++j)
          acc[i][j] = __builtin_amdgcn_mfma_f32_16x16x32_bf16(af[i], bfr[j], acc[i][j], 0, 0, 0);
    }
    __syncthreads();
  }

  // Epilogue. 64-col wave block lies entirely in one (which, head).
  const int cbase = bn * 128 + wn * 64;
  const int which = cbase / Cdim;            // 0=q 1=k 2=v
  const int h = (cbase % Cdim) >> 6;
  #pragma unroll
  for (int i = 0; i < 4; ++i) {
    int gm0 = bm * 128 + wm * 64 + i * 16 + lq * 4;
    int b = gm0 >> 9, ns0 = gm0 & 511;       // 4-run stays within one (b,ns-run)
    #pragma unroll
    for (int j = 0; j < 4; ++j) {
      int d = j * 16 + lm;
      if (which == 2) {
        short4a v4;
        #pragma unroll
        for (int r = 0; r < 4; ++r) v4[r] = (short)f2bf(acc[i][j][r]);
        *(short4a*)&vo[(size_t)((b * NH + h) * HD + d) * Nseq + ns0] = v4;
      } else {
        ushort* outp = which == 0 ? qo : ko;
        #pragma unroll
        for (int r = 0; r < 4; ++r)
          outp[(size_t)((b * NH + h) * Nseq + ns0 + r) * HD + d] = f2bf(acc[i][j][r]);
      }
    }
  }
}

// ------------- Stage 2: flash attention (V pre-transposed, LDS bias) --------
__global__ __launch_bounds__(256) void attn_kernel(
    const ushort* __restrict__ q, const ushort* __restrict__ k,
    const ushort* __restrict__ vt, const ushort* __restrict__ bt,
    ushort* __restrict__ ao)
{
  __shared__ __align__(16) ushort Qs[64 * 72];
  __shared__ __align__(16) ushort Ks[64 * 72];
  __shared__ __align__(16) ushort Vs[64 * 72];   // Vt tile: [d][n]
  __shared__ __align__(16) ushort Ps[64 * 72];
  __shared__ float biasLds[128];
  const int blk = blockIdx.x;
  const int bh = blk % (Bsz * NH);   // XCD swizzle: same head's q-tiles ->
  const int qt = blk / (Bsz * NH);   // same XCD (stride 768, 768%8==0)
  const int h = bh % NH, b = bh / NH;
  const int t = threadIdx.x;
  const int wv = t >> 6, ln = t & 63, lq = ln >> 4, lm = ln & 15;
  const size_t base = (size_t)bh * (Nseq * HD);

  #pragma unroll
  for (int i = 0; i < 2; ++i) {
    int id = t + 256 * i;
    int r = id >> 3, c = (id & 7) << 3;
    *(short8*)&Qs[r * 72 + c] =
        *(const short8*)&q[base + (size_t)(qt * 64 + r) * HD + c];
  }

  floatx4 o[4];
  #pragma unroll
  for (int i = 0; i < 4; ++i) o[i] = (floatx4)0.f;
  float mrow[4], lrow[4];
  #pragma unroll
  for (int r = 0; r < 4; ++r) { mrow[r] = -1e30f; lrow[r] = 0.f; }

  for (int kt = 0; kt < Nseq / 64; ++kt) {
    #pragma unroll
    for (int i = 0; i < 2; ++i) {
      int id = t + 256 * i;
      int r = id >> 3, c = (id & 7) << 3;
      *(short8*)&Ks[r * 72 + c] =
          *(const short8*)&k[base + (size_t)(kt * 64 + r) * HD + c];
      *(short8*)&Vs[r * 72 + c] =                      // row r = d, col c = n
          *(const short8*)&vt[base + (size_t)r * Nseq + kt * 64 + c];
    }
    // bias row for this (qt,kt): rel = qt*64-kt*64+448+i, i in [0,126]
    if (t < 127) biasLds[t] = bf2f(bt[(qt * 64 - kt * 64 + 448 + t) * NH + h]);
    __syncthreads();

    floatx4 s[4];
    #pragma unroll
    for (int cb = 0; cb < 4; ++cb) s[cb] = (floatx4)0.f;
    #pragma unroll
    for (int ks = 0; ks < 2; ++ks) {
      short8 a = *(const short8*)&Qs[(wv * 16 + lm) * 72 + ks * 32 + lq * 8];
      #pragma unroll
      for (int cb = 0; cb < 4; ++cb) {
        short8 bfr = *(const short8*)&Ks[(cb * 16 + lm) * 72 + ks * 32 + lq * 8];
        s[cb] = __builtin_amdgcn_mfma_f32_16x16x32_bf16(a, bfr, s[cb], 0, 0, 0);
      }
    }

    float pvals[4][4];
    #pragma unroll
    for (int r = 0; r < 4; ++r) {
      int row_in = wv * 16 + lq * 4 + r;
      float sv[4];
      float vmax = -1e30f;
      #pragma unroll
      for (int cb = 0; cb < 4; ++cb) {
        int col_in = cb * 16 + lm;
        float bias = biasLds[row_in - col_in + 63];
        sv[cb] = s[cb][r] * SCALE + bias;
        vmax = fmaxf(vmax, sv[cb]);
      }
      #pragma unroll
      for (int off = 8; off; off >>= 1) vmax = fmaxf(vmax, __shfl_xor(vmax, off));
      float mnew = fmaxf(mrow[r], vmax);
      float alpha = __expf(mrow[r] - mnew);
      float rsum = 0.f;
      #pragma unroll
      for (int cb = 0; cb < 4; ++cb) {
        float p = __expf(sv[cb] - mnew);
        pvals[cb][r] = p;
        rsum += p;
      }
      #pragma unroll
      for (int off = 8; off; off >>= 1) rsum += __shfl_xor(rsum, off);
      lrow[r] = lrow[r] * alpha + rsum;
      mrow[r] = mnew;
      #pragma unroll
      for (int db = 0; db < 4; ++db) o[db][r] *= alpha;
    }

    #pragma unroll
    for (int cb = 0; cb < 4; ++cb)
      #pragma unroll
      for (int r = 0; r < 4; ++r)
        Ps[(wv * 16 + lq * 4 + r) * 72 + cb * 16 + lm] = f2bf(pvals[cb][r]);

    __syncthreads();

    // O += P V : B-fragment now a vector read of Vt rows (d = db*16+lm)
    #pragma unroll
    for (int ks = 0; ks < 2; ++ks) {
      short8 a = *(const short8*)&Ps[(wv * 16 + lm) * 72 + ks * 32 + lq * 8];
      #pragma unroll
      for (int db = 0; db < 4; ++db) {
        short8 bfr = *(const short8*)&Vs[(db * 16 + lm) * 72 + ks * 32 + lq * 8];
        o[db] = __builtin_amdgcn_mfma_f32_16x16x32_bf16(a, bfr, o[db], 0, 0, 0);
      }
    }
    __syncthreads();
  }

  #pragma unroll
  for (int r = 0; r < 4; ++r) {
    int qi = qt * 64 + wv * 16 + lq * 4 + r;
    float inv = 1.f / lrow[r];
    #pragma unroll
    for (int db = 0; db < 4; ++db) {
      int d = db * 16 + lm;
      ao[(size_t)(b * Nseq + qi) * Cdim + h * HD + d] = f2bf(o[db][r] * inv);
    }
  }
}

// ------------- Stage 3: out = ao @ proj_w^T + proj_b (128x128, fp32 out) ----
__global__ __launch_bounds__(256) void proj_gemm(
    const ushort* __restrict__ a, const ushort* __restrict__ w,
    const ushort* __restrict__ pb, float* __restrict__ out)
{
  __shared__ __align__(16) ushort As[128 * 72];
  __shared__ __align__(16) ushort Ws[128 * 72];
  const int bn = blockIdx.x;   // 0..5
  const int bm = blockIdx.y;   // 0..255
  const int t = threadIdx.x;
  const int wv = t >> 6, ln = t & 63, lq = ln >> 4, lm = ln & 15;
  const int wm = wv >> 1, wn = wv & 1;

  floatx4 acc[4][4];
  #pragma unroll
  for (int i = 0; i < 4; ++i)
    #pragma unroll
    for (int j = 0; j < 4; ++j) acc[i][j] = (floatx4)0.f;

  for (int kt = 0; kt < Cdim / 64; ++kt) {
    #pragma unroll
    for (int i = 0; i < 4; ++i) {
      int id = t + 256 * i;
      int r = id >> 3, c = (id & 7) << 3;
      *(short8*)&As[r * 72 + c] =
          *(const short8*)&a[(size_t)(bm * 128 + r) * Cdim + kt * 64 + c];
      *(short8*)&Ws[r * 72 + c] =
          *(const short8*)&w[(size_t)(bn * 128 + r) * Cdim + kt * 64 + c];
    }
    __syncthreads();
    #pragma unroll
    for (int ks = 0; ks < 2; ++ks) {
      short8 af[4], bfr[4];
      #pragma unroll
      for (int i = 0; i < 4; ++i)
        af[i] = *(const short8*)&As[(wm * 64 + i * 16 + lm) * 72 + ks * 32 + lq * 8];
      #pragma unroll
      for (int j = 0; j < 4; ++j)
        bfr[j] = *(const short8*)&Ws[(wn * 64 + j * 16 + lm) * 72 + ks * 32 + lq * 8];
      #pragma unroll
      for (int i = 0; i < 4; ++i)
        #pragma unroll
        for (int j = 0; j < 4; ++j)
          acc[i][j] = __builtin_amdgcn_mfma_f32_16x16x32_bf16(af[i], bfr[j], acc[i][j], 0, 0, 0);
    }
    __syncthreads();
  }

  #pragma unroll
  for (int j = 0; j < 4; ++j) {
    int gn = bn * 128 + wn * 64 + j * 16 + lm;
    float bias = bf2f(pb[gn]);
    #pragma unroll
    for (int i = 0; i < 4; ++i) {
      #pragma unroll
      for (int r = 0; r < 4; ++r) {
        int gm = bm * 128 + wm * 64 + i * 16 + lq * 4 + r;
        out[(size_t)gm * Cdim + gn] = acc[i][j][r] + bias;
      }
    }
  }
}

extern "C" void kernel_launch(void* const* d_in, const int* in_sizes, int n_in,
                              void* d_out, int out_size, void* d_ws, size_t ws_size,
                              hipStream_t stream) {
  const float* x  = (const float*)d_in[0];   // [64,512,768] fp32
  const float* qw = (const float*)d_in[1];   // [2304,768]
  const float* pw = (const float*)d_in[2];   // [768,768]
  const float* pb = (const float*)d_in[3];   // [768]
  const float* bt = (const float*)d_in[4];   // [1023,12]
  float* out = (float*)d_out;                // [64,512,768] fp32

  constexpr int NX = Bsz * Nseq * Cdim;      // 24117248
  constexpr int NQW = 3 * Cdim * Cdim;       // 1769472
  constexpr int NPW = Cdim * Cdim;           // 589824
  constexpr int NBT = (2 * Nseq - 1) * NH;   // 12276

  ushort* qs  = (ushort*)d_ws;               // [B,H,N,hd]
  ushort* ks  = qs + QS;
  ushort* vts = ks + QS;                     // [B,H,hd,N] (transposed)
  ushort* ao  = vts + QS;                    // attn out; shares space with xb
  ushort* xb  = ao;                          // xb dead before ao written
  ushort* qwb = ao + QS;
  ushort* pwb = qwb + NQW;
  ushort* pbb = pwb + NPW;
  ushort* btb = pbb + Cdim;                  // total ws ~206 MB

  cvt8<<<(NX  + 2047) / 2048, 256, 0, stream>>>(x,  xb,  NX);
  cvt8<<<(NQW + 2047) / 2048, 256, 0, stream>>>(qw, qwb, NQW);
  cvt8<<<(NPW + 2047) / 2048, 256, 0, stream>>>(pw, pwb, NPW);
  cvt8<<<1, 256, 0, stream>>>(pb, pbb, Cdim);
  cvt1<<<(NBT + 255) / 256, 256, 0, stream>>>(bt, btb, NBT);

  qkv_gemm<<<dim3(18, 256), 256, 0, stream>>>(xb, qwb, qs, ks, vts);
  attn_kernel<<<dim3(Bsz * NH * (Nseq / 64)), 256, 0, stream>>>(qs, ks, vts, btb, ao);
  proj_gemm<<<dim3(6, 256), 256, 0, stream>>>(ao, pwb, pbb, out);
}